// Round 2
// 1697.665 us; speedup vs baseline: 1.0538x; 1.0538x over previous
//
#include <hip/hip_runtime.h>
#include <cstdint>
#include <cstddef>

#define TSTEPS 256
#define NB     256
#define NH     1024
#define NIN    105
#define NOUT   33

using half8 = __attribute__((ext_vector_type(8))) _Float16;
using f32x4 = __attribute__((ext_vector_type(4))) float;

// ws layout (halves):
//   Wrecf [0,1048576)        [64 nt][32 kk][64 lane][8]
//   Wcf   +131072            [64 nt][ 4 kk][64 lane][8]
//   Wof   +49152             [ 3 nt][32 kk][64 lane][8]
//   arr   (int*) 128 flags; xcdArr (int*) 128
//
// h history / exchange: fp16, packed into the noise buffer (float* d_in[1]):
//   h(t, group g, local row rl, col c) at half index
//       t*524288 + g*65536 + rl*1024 + c          (byte t*1MiB + g*128KiB + ...)
//   Occupies the first 64KiB of each (slab t, group g) 128KiB fp32 region.
//   Safety: group g's slab-t noise bytes are read (nzf) at its step t-1 and
//   those loads are DRAINED (B2 vmcnt0) before its flag (t done) is raised;
//   any writer of hist slab t (step-t update, group g) first polls all 16
//   group flags >= t done. Row/col partition within the group is exact.

// ---------------------------------------------------------------------------
__global__ __launch_bounds__(256) void k_convert(
    const float* __restrict__ W_sens, const float* __restrict__ W_rule,
    const float* __restrict__ W_rec,  const float* __restrict__ W_out,
    _Float16* __restrict__ Wrecf, _Float16* __restrict__ Wcf,
    _Float16* __restrict__ Wof)
{
    int tid  = blockIdx.x * 256 + threadIdx.x;
    int lane = tid & 63;
    int orow = lane & 15;
    int col0 = (lane >> 4) * 8;
    if (tid < 64 * 32 * 64) {
        int kk = (tid >> 6) & 31, n = tid >> 11;
        int o = n * 16 + orow, k0 = kk * 32 + col0;
        const float* s = W_rec + (size_t)o * NH + k0;
        _Float16* d = Wrecf + (size_t)tid * 8;
        #pragma unroll
        for (int j = 0; j < 8; ++j) d[j] = (_Float16)s[j];
    } else if (tid < 64 * 32 * 64 + 64 * 4 * 64) {
        int t2 = tid - 64 * 32 * 64;
        int kk = (t2 >> 6) & 3, n = t2 >> 8;
        int o = n * 16 + orow, k0 = kk * 32 + col0;
        _Float16* d = Wcf + (size_t)t2 * 8;
        #pragma unroll
        for (int j = 0; j < 8; ++j) {
            int k = k0 + j;
            float v = 0.f;
            if (k < 85)       v = W_sens[o * 85 + k];
            else if (k < NIN) v = W_rule[o * 20 + (k - 85)];
            d[j] = (_Float16)v;
        }
    } else {
        int t3 = tid - (64 * 32 * 64 + 64 * 4 * 64);
        int kk = (t3 >> 6) & 31, n = t3 >> 11;
        int o = n * 16 + orow, k0 = kk * 32 + col0;
        _Float16* d = Wof + (size_t)t3 * 8;
        #pragma unroll
        for (int j = 0; j < 8; ++j)
            d[j] = (o < NOUT) ? (_Float16)W_out[(size_t)o * NH + k0 + j]
                              : (_Float16)0.f;
    }
}

__global__ __launch_bounds__(256) void k_init(int* __restrict__ flags)
{
    if (threadIdx.x < 256) flags[threadIdx.x] = 0;  // arr[128] + xcdArr[128]
}

// ---------------------------------------------------------------------------
// Input GEMM for one 32-row group tile, kq0 waves only, W_in frags in regs.
// pA[nt] (rows m*16+q*4+r, cols s*64+nt*16+mrow) = x[t]·W_in^T + noise + bias.
// ---------------------------------------------------------------------------
__device__ __forceinline__ void in_gemm(
    const float* __restrict__ x, int tstep, int g, int m, int mrow, int q,
    const half8 wcb[4][4], const float nzf[4][4], const float bias[4],
    f32x4 pA[4])
{
    const float* xrow = x + ((size_t)tstep * NB + g * 32 + m * 16 + mrow) * NIN;
    half8 af[4];
    #pragma unroll
    for (int kk = 0; kk < 4; ++kk) {
        #pragma unroll
        for (int j = 0; j < 8; ++j) {
            int c = kk * 32 + q * 8 + j;
            float v = (c < NIN) ? xrow[c] : 0.f;   // only kk==3 actually masks
            af[kk][j] = (_Float16)v;
        }
    }
    #pragma unroll
    for (int nt = 0; nt < 4; ++nt) {
        f32x4 c = { nzf[nt][0] + bias[nt], nzf[nt][1] + bias[nt],
                    nzf[nt][2] + bias[nt], nzf[nt][3] + bias[nt] };
        #pragma unroll
        for (int kk = 0; kk < 4; ++kk)
            c = __builtin_amdgcn_mfma_f32_16x16x32_f16(af[kk], wcb[nt][kk], c,
                                                       0, 0, 0);
        pA[nt] = c;
    }
}

// ---------------------------------------------------------------------------
// K2: 128 blocks = 8 groups(32 rows, g=blk&7 -> XCD-affine) x 16 slices(64 cols).
// Per step: B0 (poll release) -> K-loop -> B1 (lgkm only) -> update+fp16 hist
// store -> B2 (vmcnt0) -> flag -> shadow: input-GEMM for t+1.
// Flag protocol: 0 init, 1 = prologue loads drained, t+2 = step t done.
// Fast path signaling: producer = plain write-through store (lands in shared
// XCD L2); consumer = buffer_inv sc0 (L1 inv) + plain volatile load (L2 read).
// No reliance on sc0-load bypass semantics.
// ---------------------------------------------------------------------------
__global__ __launch_bounds__(512, 1) void k_rnn(
    const float* __restrict__ x, float* __restrict__ noise,
    const float* __restrict__ b_sens, const float* __restrict__ b_rec,
    const _Float16* __restrict__ Wrecf, const _Float16* __restrict__ Wcf,
    int* __restrict__ arr, int* __restrict__ xcdArr)
{
    __shared__ _Float16 Wl[4 * 32 * 64 * 8];   // 128 KB [nt][kk][lane][8]
    __shared__ float red[3][8][64][4];         // 24 KB  [kq-1][m*4+nt][lane][r]
    __shared__ int sFast;

    const int tid  = threadIdx.x;
    const int blk  = blockIdx.x;
    const int g    = blk & 7, s = blk >> 3;
    const int wave = tid >> 6, lane = tid & 63;
    const int m    = wave & 1, kq = wave >> 1;
    const int mrow = lane & 15, q = lane >> 4;
    const half8* Wc8 = (const half8*)Wcf;
    _Float16* hist = (_Float16*)noise;
    volatile int* varr = (volatile int*)arr;

    // W slice: global ntiles [4s, 4s+4) -> contiguous 128 KB
    {
        const float4* src = (const float4*)(Wrecf + (size_t)(4 * s) * (32 * 64 * 8));
        float4* dst = (float4*)Wl;
        for (int i = tid; i < 8192; i += 512) dst[i] = src[i];
    }

    // ---- XCD uniformity check (runtime-select fast/safe path) ----
    int xcd;
    asm volatile("s_getreg_b32 %0, hwreg(20, 0, 4)" : "=s"(xcd)); // HW_REG_XCC_ID
    if (tid == 0)
        __hip_atomic_store(&xcdArr[blk], xcd + 1, __ATOMIC_RELEASE,
                           __HIP_MEMORY_SCOPE_AGENT);
    if (wave == 0) {
        int idx = g + (lane & 15) * 8;   // my group's 16 block ids: g + 8*s
        int v = 0;
        for (int it = 0; it < (1 << 22); ++it) {
            v = __hip_atomic_load(&xcdArr[idx], __ATOMIC_ACQUIRE,
                                  __HIP_MEMORY_SCOPE_AGENT);
            if (__all(v >= 1)) break;
            __builtin_amdgcn_s_sleep(8);
        }
        if (lane == 0) sFast = __all(v == xcd + 1) ? 1 : 0;
    }
    __syncthreads();
    const bool fast = (sFast != 0);

    float hm[4][4];     // kq0: fp32 master h
    f32x4 pA[4];        // kq0: input tile for current t
    float nzf[4][4];    // kq0: noise for next t (early-loaded)
    float bias[4];
    half8 wcb[4][4];    // kq0: W_in B-frags, register-resident
    #pragma unroll
    for (int nt = 0; nt < 4; ++nt)
        #pragma unroll
        for (int r = 0; r < 4; ++r) hm[nt][r] = 0.f;

    if (kq == 0) {
        #pragma unroll
        for (int nt = 0; nt < 4; ++nt) {
            int o = s * 64 + nt * 16 + mrow;
            bias[nt] = b_sens[o] + b_rec[o];
            #pragma unroll
            for (int kk = 0; kk < 4; ++kk)
                wcb[nt][kk] = Wc8[((4 * s + nt) * 4 + kk) * 64 + lane];
            #pragma unroll
            for (int r = 0; r < 4; ++r)
                nzf[nt][r] = noise[(size_t)(g * 32 + m * 16 + q * 4 + r) * NH
                                   + s * 64 + nt * 16 + mrow];
        }
    }
    __syncthreads();               // full drain: prologue noise loads done
    if (tid == 0) {                // prologue-done flag = 1
        if (fast) varr[g * 16 + s] = 1;
        else __hip_atomic_store(&arr[g * 16 + s], 1, __ATOMIC_RELAXED,
                                __HIP_MEMORY_SCOPE_AGENT);
    }
    if (kq == 0)
        in_gemm(x, 0, g, m, mrow, q, wcb, nzf, bias, pA);   // pA for t=0

    for (int t = 0; t < TSTEPS; ++t) {
        // ---- early loads: noise slab t+1 (drained by B2 -> safe vs writers) --
        if (kq == 0 && t + 1 < TSTEPS) {
            #pragma unroll
            for (int nt = 0; nt < 4; ++nt)
                #pragma unroll
                for (int r = 0; r < 4; ++r)
                    nzf[nt][r] = noise[((size_t)(t + 1) * NB + g * 32 + m * 16
                                        + q * 4 + r) * NH
                                       + s * 64 + nt * 16 + mrow];
        }
        // ---- 1. wave0 polls all 16 slices of my group at >= t+1 ----
        if (wave == 0) {
            int idx = g * 16 + (lane & 15);
            if (fast) {
                for (int it = 0; it < (1 << 22); ++it) {
                    asm volatile("buffer_inv sc0" ::: "memory");  // L1 inv
                    int v = varr[idx];                            // L2 read
                    if (__all(v >= t + 1)) break;
                    __builtin_amdgcn_s_sleep(1);
                }
            } else {
                for (int it = 0; it < (1 << 22); ++it) {
                    int v = __hip_atomic_load(&arr[idx], __ATOMIC_RELAXED,
                                              __HIP_MEMORY_SCOPE_AGENT);
                    if (__all(v >= t + 1)) break;
                    __builtin_amdgcn_s_sleep(1);
                }
            }
        }
        asm volatile("s_barrier" ::: "memory");              // B0
        if (!fast) __builtin_amdgcn_fence(__ATOMIC_ACQUIRE, "agent");
        // fast: wave0's in-loop buffer_inv already invalidated the CU's L1;
        // no other wave issued loads of shared data since (parked at B0).

        // ---- 2. K-loop: A = fp16 h slab t-1 (L2), B = LDS W slice ----
        f32x4 acc[4];
        #pragma unroll
        for (int nt = 0; nt < 4; ++nt) acc[nt] = (f32x4){0.f, 0.f, 0.f, 0.f};
        if (t > 0) {
            const _Float16* hR = hist + (size_t)(t - 1) * 524288
                                      + (size_t)g * 65536
                                      + (size_t)(m * 16 + mrow) * 1024
                                      + kq * 256 + q * 8;
            #pragma unroll
            for (int kkl = 0; kkl < 8; ++kkl) {
                half8 a = *(const half8*)(hR + kkl * 32);
                #pragma unroll
                for (int nt = 0; nt < 4; ++nt) {
                    half8 b = *(const half8*)&Wl[((nt * 32 + kq * 8 + kkl) * 64
                                                  + lane) * 8];
                    acc[nt] = __builtin_amdgcn_mfma_f32_16x16x32_f16(a, b,
                                                                acc[nt], 0, 0, 0);
                }
            }
        }
        // ---- 3. parallel reduction: kq1..3 publish, one barrier ----
        if (kq != 0) {
            #pragma unroll
            for (int nt = 0; nt < 4; ++nt)
                *(f32x4*)&red[kq - 1][m * 4 + nt][lane][0] = acc[nt];
        }
        asm volatile("s_waitcnt lgkmcnt(0)\n\ts_barrier" ::: "memory");  // B1

        // ---- 4. update + fp16 history store (kq0 waves own 32x64 tile) ----
        if (kq == 0) {
            const size_t hb = (size_t)t * 524288 + (size_t)g * 65536;
            #pragma unroll
            for (int nt = 0; nt < 4; ++nt) {
                f32x4 r0 = *(const f32x4*)&red[0][m * 4 + nt][lane][0];
                f32x4 r1 = *(const f32x4*)&red[1][m * 4 + nt][lane][0];
                f32x4 r2 = *(const f32x4*)&red[2][m * 4 + nt][lane][0];
                #pragma unroll
                for (int r = 0; r < 4; ++r) {
                    float v  = acc[nt][r] + r0[r] + r1[r] + r2[r] + pA[nt][r];
                    float sp = fmaxf(v, 0.f) + __logf(1.f + __expf(-fabsf(v)));
                    float hn = 0.2f * sp + 0.8f * hm[nt][r];
                    hm[nt][r] = hn;
                    hist[hb + (size_t)(m * 16 + q * 4 + r) * 1024
                            + s * 64 + nt * 16 + mrow] = (_Float16)hn;
                }
            }
        }
        // drain hist stores + early noise loads, then signal
        asm volatile("s_waitcnt vmcnt(0) lgkmcnt(0)\n\ts_barrier" ::: "memory"); // B2
        if (tid == 0) {
            if (fast) varr[g * 16 + s] = t + 2;   // write-through -> local L2
            else {
                __builtin_amdgcn_fence(__ATOMIC_RELEASE, "agent");
                __hip_atomic_store(&arr[g * 16 + s], t + 2, __ATOMIC_RELAXED,
                                   __HIP_MEMORY_SCOPE_AGENT);
            }
        }
        // ---- 5. shadow: input GEMM for t+1 (overlaps peers' poll/K-loop) ----
        if (kq == 0 && t + 1 < TSTEPS)
            in_gemm(x, t + 1, g, m, mrow, q, wcb, nzf, bias, pA);
    }
}

// ---------------------------------------------------------------------------
__global__ __launch_bounds__(256) void k_out(
    const _Float16* __restrict__ h16, const _Float16* __restrict__ Wof,
    const float* __restrict__ b_out, float* __restrict__ y)
{
    int blk  = blockIdx.x;
    int wave = threadIdx.x >> 6, lane = threadIdx.x & 63;
    int mrow = lane & 15, q = lane >> 4;
    int t  = blk >> 2;
    int b  = (blk & 3) * 64 + wave * 16 + mrow;
    size_t hb = (size_t)t * 524288 + (size_t)(b >> 5) * 65536
              + (size_t)(b & 31) * 1024;
    const half8* Wo8 = (const half8*)Wof;

    f32x4 acc[3];
    #pragma unroll
    for (int nt = 0; nt < 3; ++nt) acc[nt] = (f32x4){0.f, 0.f, 0.f, 0.f};

    #pragma unroll 4
    for (int kk = 0; kk < 32; ++kk) {
        half8 a = *(const half8*)(h16 + hb + kk * 32 + q * 8);
        #pragma unroll
        for (int nt = 0; nt < 3; ++nt) {
            half8 bb = Wo8[(nt * 32 + kk) * 64 + lane];
            acc[nt] = __builtin_amdgcn_mfma_f32_16x16x32_f16(a, bb, acc[nt],
                                                             0, 0, 0);
        }
    }
    #pragma unroll
    for (int nt = 0; nt < 3; ++nt) {
        int o = nt * 16 + mrow;
        if (o < NOUT) {
            float bo = b_out[o];
            #pragma unroll
            for (int r = 0; r < 4; ++r) {
                size_t R = (size_t)blk * 64 + wave * 16 + q * 4 + r;
                y[R * NOUT + o] = acc[nt][r] + bo;
            }
        }
    }
}

// ---------------------------------------------------------------------------
extern "C" void kernel_launch(void* const* d_in, const int* in_sizes, int n_in,
                              void* d_out, int out_size, void* d_ws, size_t ws_size,
                              hipStream_t stream) {
    const float* x      = (const float*)d_in[0];
    float*       noise  = (float*)d_in[1];   // also carries fp16 h history
    const float* W_sens = (const float*)d_in[2];
    const float* b_sens = (const float*)d_in[3];
    const float* W_rule = (const float*)d_in[4];
    const float* W_rec  = (const float*)d_in[5];
    const float* b_rec  = (const float*)d_in[6];
    const float* W_out  = (const float*)d_in[7];
    const float* b_out  = (const float*)d_in[8];
    float*       y      = (float*)d_out;

    _Float16* wsp   = (_Float16*)d_ws;
    _Float16* Wrecf = wsp;
    _Float16* Wcf   = Wrecf + 1048576;
    _Float16* Wof   = Wcf   + 131072;
    int*      arr   = (int*)(Wof + 49152);   // 128 flags
    int*      xcdArr= arr + 128;             // 128 xcd ids

    k_convert<<<dim3(600), dim3(256), 0, stream>>>(W_sens, W_rule, W_rec, W_out,
                                                   Wrecf, Wcf, Wof);
    k_init<<<dim3(1), dim3(256), 0, stream>>>(arr);
    k_rnn<<<dim3(128), dim3(512), 0, stream>>>(x, noise, b_sens, b_rec,
                                               Wrecf, Wcf, arr, xcdArr);
    k_out<<<dim3(1024), dim3(256), 0, stream>>>((const _Float16*)noise, Wof,
                                                b_out, y);
}